// Round 4
// baseline (93.551 us; speedup 1.0000x reference)
//
#include <hip/hip_runtime.h>

// SpectralInverse: out[b,p,o] = sum_f cos(2*pi*(y[p]·y_w[f] + y_b[f])) * G[b,f,o] + u_b[o]
// where G[b,f,o] = (sum_m h[b,f,m] * u_w[o,m]) / n_grid   (sin(x)~=x folding, err ~1e-10)
// Shapes: B=4, F=128, Cin=64, Cout=8, D=3, NPTS=48^3=110592 per batch.
//
// R4: pure-VALU o-contraction (COUT=8 too small to need MFMA). No bf16, no
// MFMA, no LDS in the main kernel. Per-batch 6 KB param table
// T[b][f] = {wx,wy,wz,yb, G0..G7} read via wave-uniform (scalar) loads.
// Diagnostic for the R1-R3 mystery 35 us: isolates v_cos rate from
// bf16-pack/MFMA-hazard overhead.

#define NPTS      110592
#define NFREQ     128
#define CIN       64
#define COUT      8
#define THR       128                 // threads per block (2 waves)
#define P_PER_T   2
#define PTS_BLK   (THR * P_PER_T)     // 256 points per block
#define BLK_PER_B (NPTS / PTS_BLK)    // 432

typedef float f32x2 __attribute__((ext_vector_type(2)));

// ---------------------------------------------------------------------------
// Kernel 1: T[b][f][12] = {wx, wy, wz, yb, G[b,f,0..7]},  G = (h·u_w)/NPTS.
// grid = 2 blocks x 256 threads; thread id = b*128 + f.
// ---------------------------------------------------------------------------
__global__ __launch_bounds__(256) void spectral_prep(
    const float* __restrict__ h,      // (4,128,64)
    const float* __restrict__ u_w,    // (8,64)
    const float* __restrict__ y_w,    // (128,3)
    const float* __restrict__ y_b,    // (128,)
    float* __restrict__ T)            // (4,128,12)
{
    __shared__ float uw[COUT * CIN];  // 2 KB
    const int t = threadIdx.x;
    for (int i = t; i < COUT * CIN; i += 256) uw[i] = u_w[i];
    __syncthreads();

    const int id = blockIdx.x * 256 + t;   // 0..511
    const int b = id >> 7, f = id & 127;

    const float4* hp = (const float4*)(h + ((size_t)(b * NFREQ + f)) * CIN);
    float g[COUT] = {0, 0, 0, 0, 0, 0, 0, 0};
    for (int m4 = 0; m4 < CIN / 4; ++m4) {
        float4 a = hp[m4];
#pragma unroll
        for (int o = 0; o < COUT; ++o) {
            float4 u = *(const float4*)&uw[o * CIN + m4 * 4];
            g[o] += a.x * u.x + a.y * u.y + a.z * u.z + a.w * u.w;
        }
    }
    float* dst = T + (size_t)id * 12;
    dst[0] = y_w[f * 3 + 0];
    dst[1] = y_w[f * 3 + 1];
    dst[2] = y_w[f * 3 + 2];
    dst[3] = y_b[f];
#pragma unroll
    for (int o = 0; o < COUT; ++o) dst[4 + o] = g[o] * (1.0f / (float)NPTS);
}

// ---------------------------------------------------------------------------
// Kernel 2: main. grid = 4*432 = 1728 blocks x 128 threads.
// Thread handles 2 points (p0 = pbase+t, p1 = pbase+128+t). Per f:
//   Y pair via 3 pk-FMA, fract+cos per point, 8 o-accs via 4 pk-FMA each.
// Table reads are wave-uniform -> scalar loads (K$-resident, 6 KB/batch).
// ---------------------------------------------------------------------------
__global__ __launch_bounds__(THR) void spectral_main(
    const float* __restrict__ y,      // (4,110592,3)
    const float* __restrict__ T,      // (4,128,12)
    const float* __restrict__ u_b,    // (8,)
    float*       __restrict__ out)    // (4,110592,8)
{
    const int t     = threadIdx.x;
    const int b     = blockIdx.x / BLK_PER_B;
    const int pbase = (blockIdx.x % BLK_PER_B) * PTS_BLK;
    const int p0    = pbase + t;
    const int p1    = pbase + THR + t;

    const float* yp = y + (size_t)b * NPTS * 3;
    f32x2 X  = {yp[p0 * 3 + 0], yp[p1 * 3 + 0]};
    f32x2 Yc = {yp[p0 * 3 + 1], yp[p1 * 3 + 1]};
    f32x2 Z  = {yp[p0 * 3 + 2], yp[p1 * 3 + 2]};

    const float* Tb = T + (size_t)b * NFREQ * 12;

    f32x2 accA[4] = {{0, 0}, {0, 0}, {0, 0}, {0, 0}};   // point p0, o-pairs
    f32x2 accB[4] = {{0, 0}, {0, 0}, {0, 0}, {0, 0}};   // point p1, o-pairs

#pragma unroll 4
    for (int f = 0; f < NFREQ; ++f) {
        const float* tf = Tb + f * 12;
        float wx = tf[0], wy = tf[1], wz = tf[2], wb = tf[3];
        f32x2 Yv = __builtin_elementwise_fma((f32x2){wx, wx}, X,
                   __builtin_elementwise_fma((f32x2){wy, wy}, Yc,
                   __builtin_elementwise_fma((f32x2){wz, wz}, Z,
                                             (f32x2){wb, wb})));
        // cos(2*pi*Y): v_cos takes revolutions; v_fract is exact range reduction
        float c0 = __builtin_amdgcn_cosf(__builtin_amdgcn_fractf(Yv[0]));
        float c1 = __builtin_amdgcn_cosf(__builtin_amdgcn_fractf(Yv[1]));
        f32x2 cc0 = {c0, c0}, cc1 = {c1, c1};
#pragma unroll
        for (int oo = 0; oo < 4; ++oo) {
            f32x2 g = *(const f32x2*)(tf + 4 + 2 * oo);
            accA[oo] = __builtin_elementwise_fma(cc0, g, accA[oo]);
            accB[oo] = __builtin_elementwise_fma(cc1, g, accB[oo]);
        }
    }

    float ub[COUT];
#pragma unroll
    for (int o = 0; o < COUT; ++o) ub[o] = u_b[o];

    const size_t obase = (size_t)b * NPTS * COUT;
    float4 vA0 = {accA[0][0] + ub[0], accA[0][1] + ub[1],
                  accA[1][0] + ub[2], accA[1][1] + ub[3]};
    float4 vA1 = {accA[2][0] + ub[4], accA[2][1] + ub[5],
                  accA[3][0] + ub[6], accA[3][1] + ub[7]};
    float4 vB0 = {accB[0][0] + ub[0], accB[0][1] + ub[1],
                  accB[1][0] + ub[2], accB[1][1] + ub[3]};
    float4 vB1 = {accB[2][0] + ub[4], accB[2][1] + ub[5],
                  accB[3][0] + ub[6], accB[3][1] + ub[7]};
    *(float4*)(out + obase + (size_t)p0 * COUT)     = vA0;
    *(float4*)(out + obase + (size_t)p0 * COUT + 4) = vA1;
    *(float4*)(out + obase + (size_t)p1 * COUT)     = vB0;
    *(float4*)(out + obase + (size_t)p1 * COUT + 4) = vB1;
}

// ---------------------------------------------------------------------------
extern "C" void kernel_launch(void* const* d_in, const int* in_sizes, int n_in,
                              void* d_out, int out_size, void* d_ws, size_t ws_size,
                              hipStream_t stream)
{
    const float* h   = (const float*)d_in[0];
    const float* y   = (const float*)d_in[1];
    const float* y_w = (const float*)d_in[2];
    const float* y_b = (const float*)d_in[3];
    const float* u_w = (const float*)d_in[4];
    const float* u_b = (const float*)d_in[5];
    float* out = (float*)d_out;
    float* T   = (float*)d_ws;   // 4*128*12*4 = 24576 B

    spectral_prep<<<2, 256, 0, stream>>>(h, u_w, y_w, y_b, T);
    spectral_main<<<4 * BLK_PER_B, THR, 0, stream>>>(y, T, u_b, out);
}

// Round 5
// 82.726 us; speedup vs baseline: 1.1309x; 1.1309x over previous
//
#include <hip/hip_runtime.h>
#include <hip/hip_bf16.h>

// SpectralInverse: out[b,p,o] = sum_f cos(2*pi*(y[p]·y_w[f] + y_b[f])) * G[b,f,o] + u_b[o]
// where G[b,f,o] = (sum_m h[b,f,m] * u_w[o,m]) / n_grid   (sin(x)~=x folding, err ~1e-10)
// Shapes: B=4, F=128, Cin=64, Cout=8, D=3, NPTS=48^3=110592 per batch.
//
// R5 = R3 minus v_fract: v_cos_f32 input is revolutions, HW-valid to |x|<=256;
// here |Y| <= 3*(30/sqrt(3)) + 1/sqrt(3) ~= 52.5, so no explicit range
// reduction needed (phase err ~2^-18 rev << bf16 quantization, matches the
// fp32 reference's own ULP at this magnitude).
// Session model: harness fixed overhead ~80 us (268 MB ws poison fill = 40.6 us
// at 82% HBM peak + fills/restores/graph gaps); kernel-side is ~5-6 us.

#define NPTS      110592
#define NFREQ     128
#define CIN       64
#define COUT      8
#define PTS_BLK   256                 // points per block (4 waves x 64 pts)
#define BLK_PER_B (NPTS / PTS_BLK)    // 432
#define GT_STRIDE 136                 // bf16 elems; breaks pow2 bank stride

typedef __bf16 bf16x8 __attribute__((ext_vector_type(8)));
typedef float  f32x4  __attribute__((ext_vector_type(4)));
typedef float  f32x2  __attribute__((ext_vector_type(2)));

// ---------------------------------------------------------------------------
// Kernel 1: G[b][n][f] (o-major, n padded to 16 with zeros) bf16 into ws,
// plus packed freq params pk[f] = (w0,w1,w2,yb) float4.
// ---------------------------------------------------------------------------
__global__ __launch_bounds__(256) void spectral_prep(
    const float* __restrict__ h,      // (4,128,64)
    const float* __restrict__ u_w,    // (8,64)
    const float* __restrict__ y_w,    // (128,3)
    const float* __restrict__ y_b,    // (128,)
    __bf16* __restrict__ gws,         // (4,16,128)
    float4* __restrict__ pkws)        // (128,)
{
    int b  = blockIdx.x >> 3;
    int fg = blockIdx.x & 7;
    int t  = threadIdx.x;
    int f  = fg * 16 + (t >> 4);
    int n  = t & 15;

    float acc = 0.0f;
    if (n < COUT) {
        const float4* hp = (const float4*)(h + ((size_t)(b * NFREQ + f)) * CIN);
        const float4* up = (const float4*)(u_w + (size_t)n * CIN);
#pragma unroll
        for (int m = 0; m < CIN / 4; ++m) {
            float4 a = hp[m], c = up[m];
            acc += a.x * c.x + a.y * c.y + a.z * c.z + a.w * c.w;
        }
        acc *= (1.0f / (float)NPTS);
    }
    gws[(size_t)b * (16 * NFREQ) + n * NFREQ + f] = (__bf16)acc;

    if (blockIdx.x == 0 && t < NFREQ) {
        pkws[t] = make_float4(y_w[3 * t], y_w[3 * t + 1], y_w[3 * t + 2], y_b[t]);
    }
}

// ---------------------------------------------------------------------------
// Kernel 2: main. grid = 4*432 = 1728 blocks, 256 threads (4 waves).
// Wave wv: points pbase + wv*64 + rt*16 + (lane&15), rt = 0..3.
// A-fragments built in-register (layout row=lane&15, k=quad*8+j, verified
// R1-R4 passes); B-frag (G^T) from LDS; 4 MFMA per 32-freq step.
// ---------------------------------------------------------------------------
__global__ __launch_bounds__(256, 4) void spectral_main(
    const float*  __restrict__ y,     // (4,110592,3)
    const __bf16* __restrict__ gws,   // (4,16,128)
    const float4* __restrict__ pkws,  // (128,)
    const float*  __restrict__ u_b,   // (8,)
    float*        __restrict__ out)   // (4,110592,8)
{
    __shared__ __align__(16) __bf16 GT_lds[16 * GT_STRIDE];   // 4352 B
    __shared__ __align__(16) float4 pk_lds[NFREQ];            // 2048 B
    __shared__ __align__(16) float  y_lds[PTS_BLK * 3];       // 3072 B

    const int t     = threadIdx.x;
    const int b     = blockIdx.x / BLK_PER_B;
    const int pbase = (blockIdx.x % BLK_PER_B) * PTS_BLK;

    // ---- staging (coalesced, once per block) ----
    {
        bf16x8 g = ((const bf16x8*)(gws + (size_t)b * (16 * NFREQ)))[t];
        *(bf16x8*)&GT_lds[(t >> 4) * GT_STRIDE + (t & 15) * 8] = g;
        if (t < NFREQ) pk_lds[t] = pkws[t];
        if (t < PTS_BLK * 3 / 4)
            ((float4*)y_lds)[t] = ((const float4*)(y + ((size_t)b * NPTS + pbase) * 3))[t];
    }
    __syncthreads();

    const int lane = t & 63;
    const int wv   = t >> 6;
    const int quad = lane >> 4;
    const int l15  = lane & 15;

    // y coords for this thread's 4 points, paired for v_pk_fma_f32
    f32x2 y0a, y1a, y2a, y0b, y1b, y2b;
    {
        int p0 = wv * 64 + 0 * 16 + l15;
        int p1 = wv * 64 + 1 * 16 + l15;
        int p2 = wv * 64 + 2 * 16 + l15;
        int p3 = wv * 64 + 3 * 16 + l15;
        y0a = (f32x2){y_lds[p0 * 3 + 0], y_lds[p1 * 3 + 0]};
        y1a = (f32x2){y_lds[p0 * 3 + 1], y_lds[p1 * 3 + 1]};
        y2a = (f32x2){y_lds[p0 * 3 + 2], y_lds[p1 * 3 + 2]};
        y0b = (f32x2){y_lds[p2 * 3 + 0], y_lds[p3 * 3 + 0]};
        y1b = (f32x2){y_lds[p2 * 3 + 1], y_lds[p3 * 3 + 1]};
        y2b = (f32x2){y_lds[p2 * 3 + 2], y_lds[p3 * 3 + 2]};
    }

    f32x4 acc[4] = {{0,0,0,0},{0,0,0,0},{0,0,0,0},{0,0,0,0}};
    const __bf16* bptr = &GT_lds[l15 * GT_STRIDE + quad * 8];
    const float4* wp   = &pk_lds[quad * 8];

#pragma clang loop unroll(disable)
    for (int k0 = 0; k0 < NFREQ; k0 += 32) {
        bf16x8 a0, a1, a2, a3;
#pragma unroll
        for (int j = 0; j < 8; ++j) {
            float4 w = wp[k0 + j];
            f32x2 wx = {w.x, w.x}, wy = {w.y, w.y}, wz = {w.z, w.z}, wb = {w.w, w.w};
            f32x2 Ya = __builtin_elementwise_fma(wx, y0a,
                       __builtin_elementwise_fma(wy, y1a,
                       __builtin_elementwise_fma(wz, y2a, wb)));
            f32x2 Yb = __builtin_elementwise_fma(wx, y0b,
                       __builtin_elementwise_fma(wy, y1b,
                       __builtin_elementwise_fma(wz, y2b, wb)));
            // v_cos_f32: cos(2*pi*x), x in revolutions; |Y|<=52.5 is within
            // the HW range-reduction domain -> no v_fract needed.
            a0[j] = (__bf16)__builtin_amdgcn_cosf(Ya[0]);
            a1[j] = (__bf16)__builtin_amdgcn_cosf(Ya[1]);
            a2[j] = (__bf16)__builtin_amdgcn_cosf(Yb[0]);
            a3[j] = (__bf16)__builtin_amdgcn_cosf(Yb[1]);
        }
        bf16x8 bf = *(const bf16x8*)(bptr + k0);
        acc[0] = __builtin_amdgcn_mfma_f32_16x16x32_bf16(a0, bf, acc[0], 0, 0, 0);
        acc[1] = __builtin_amdgcn_mfma_f32_16x16x32_bf16(a1, bf, acc[1], 0, 0, 0);
        acc[2] = __builtin_amdgcn_mfma_f32_16x16x32_bf16(a2, bf, acc[2], 0, 0, 0);
        acc[3] = __builtin_amdgcn_mfma_f32_16x16x32_bf16(a3, bf, acc[3], 0, 0, 0);
    }

    // ---- epilogue: C/D layout col=lane&15, row=quad*4+reg (verified R1-R4) ----
    if (l15 < COUT) {
        float ub = u_b[l15];
        size_t base = ((size_t)b * NPTS + pbase) * COUT;
#pragma unroll
        for (int rt = 0; rt < 4; ++rt) {
#pragma unroll
            for (int q = 0; q < 4; ++q) {
                int pr = wv * 64 + rt * 16 + quad * 4 + q;
                out[base + (size_t)pr * COUT + l15] = acc[rt][q] + ub;
            }
        }
    }
}

// ---------------------------------------------------------------------------
extern "C" void kernel_launch(void* const* d_in, const int* in_sizes, int n_in,
                              void* d_out, int out_size, void* d_ws, size_t ws_size,
                              hipStream_t stream)
{
    const float* h   = (const float*)d_in[0];
    const float* y   = (const float*)d_in[1];
    const float* y_w = (const float*)d_in[2];
    const float* y_b = (const float*)d_in[3];
    const float* u_w = (const float*)d_in[4];
    const float* u_b = (const float*)d_in[5];
    float* out = (float*)d_out;
    __bf16* gws  = (__bf16*)d_ws;                       // 16 KB
    float4* pkws = (float4*)((char*)d_ws + 16384);      //  2 KB

    spectral_prep<<<32, 256, 0, stream>>>(h, u_w, y_w, y_b, gws, pkws);
    spectral_main<<<4 * BLK_PER_B, 256, 0, stream>>>(y, gws, pkws, u_b, out);
}